// Round 1
// baseline (123.375 us; speedup 1.0000x reference)
//
#include <hip/hip_runtime.h>
#include <hip/hip_bf16.h>

// Problem constants (B, N, S, D) from reference
#define B_SZ 64
#define N_Q 32
#define S_D 256
#define D_DIM 128

typedef __attribute__((ext_vector_type(8))) short bf16x8;
typedef __attribute__((ext_vector_type(4))) float f32x4;

static __device__ __forceinline__ unsigned short f2bf(float f) {
    __hip_bfloat16 h = __float2bfloat16(f);
    return *reinterpret_cast<unsigned short*>(&h);
}

__global__ __launch_bounds__(256) void cvt_f32_bf16(const float* __restrict__ src,
                                                    unsigned short* __restrict__ dst,
                                                    int n4) {
    int i = blockIdx.x * 256 + threadIdx.x;
    if (i >= n4) return;
    float4 v = reinterpret_cast<const float4*>(src)[i];
    ushort4 o;
    o.x = f2bf(v.x); o.y = f2bf(v.y); o.z = f2bf(v.z); o.w = f2bf(v.w);
    reinterpret_cast<ushort4*>(dst)[i] = o;
}

// One workgroup per (b, c) pair. c in [0,64): in-batch docs; c == 64: neg docs of b.
// Computes scores[b*65 + c] = sum_n max_s  q[b,n] . docs[c_or_b, s]
__global__ __launch_bounds__(256) void maxsim_kernel(const unsigned short* __restrict__ Qb,
                                                     const unsigned short* __restrict__ Db,
                                                     const unsigned short* __restrict__ Nb,
                                                     float* __restrict__ scores) {
    const int c = blockIdx.x;      // 0..64
    const int b = blockIdx.y;      // 0..63

    const unsigned short* qptr = Qb + (size_t)b * N_Q * D_DIM;
    const unsigned short* dptr = (c < B_SZ) ? (Db + (size_t)c * S_D * D_DIM)
                                            : (Nb + (size_t)b * S_D * D_DIM);

    const int tid  = threadIdx.x;
    const int wave = tid >> 6;     // 0..3, each wave owns 64 columns of s
    const int lane = tid & 63;
    const int l15  = lane & 15;
    const int l4   = lane >> 4;    // 0..3
    const int s_base = wave * 64;

    // acc[mtile][ntile]: C tile (16x16); rows n = mtile*16 + l4*4 + reg, col s = s_base + ntile*16 + l15
    f32x4 acc[2][4] = {};

    #pragma unroll
    for (int kk = 0; kk < 4; ++kk) {         // K = 128 in steps of 32
        const int ko = kk * 32 + l4 * 8;
        // A fragment: A[m = l15][k = l4*8 + j] -> 8 contiguous bf16 along D
        bf16x8 a0 = *reinterpret_cast<const bf16x8*>(qptr + (size_t)(0 * 16 + l15) * D_DIM + ko);
        bf16x8 a1 = *reinterpret_cast<const bf16x8*>(qptr + (size_t)(1 * 16 + l15) * D_DIM + ko);
        #pragma unroll
        for (int nt = 0; nt < 4; ++nt) {
            const int s = s_base + nt * 16 + l15;
            // B fragment: B[k][n = l15] = docs[s = n][k] -> 8 contiguous bf16 along D
            bf16x8 bf = *reinterpret_cast<const bf16x8*>(dptr + (size_t)s * D_DIM + ko);
            acc[0][nt] = __builtin_amdgcn_mfma_f32_16x16x32_bf16(a0, bf, acc[0][nt], 0, 0, 0);
            acc[1][nt] = __builtin_amdgcn_mfma_f32_16x16x32_bf16(a1, bf, acc[1][nt], 0, 0, 0);
        }
    }

    // Reduce: max over s (columns), then sum over n (rows).
    __shared__ float wmax[4][N_Q];
    #pragma unroll
    for (int mt = 0; mt < 2; ++mt) {
        #pragma unroll
        for (int reg = 0; reg < 4; ++reg) {
            // max over this lane's 4 column-tiles (same l15 within each tile)
            float m = fmaxf(fmaxf(acc[mt][0][reg], acc[mt][1][reg]),
                            fmaxf(acc[mt][2][reg], acc[mt][3][reg]));
            // max across the 16 distinct columns (lanes differing in bits 0..3; row is bits 4..5 + reg)
            m = fmaxf(m, __shfl_xor(m, 1, 64));
            m = fmaxf(m, __shfl_xor(m, 2, 64));
            m = fmaxf(m, __shfl_xor(m, 4, 64));
            m = fmaxf(m, __shfl_xor(m, 8, 64));
            if (l15 == 0) wmax[wave][mt * 16 + l4 * 4 + reg] = m;  // row-max over this wave's 64 cols
        }
    }
    __syncthreads();

    if (tid < N_Q) {
        // max over the 4 waves' column slices -> max over all 256 s for row tid
        float v = fmaxf(fmaxf(wmax[0][tid], wmax[1][tid]),
                        fmaxf(wmax[2][tid], wmax[3][tid]));
        // sum over the 32 rows (lanes 0..31 of wave 0)
        v += __shfl_xor(v, 1, 64);
        v += __shfl_xor(v, 2, 64);
        v += __shfl_xor(v, 4, 64);
        v += __shfl_xor(v, 8, 64);
        v += __shfl_xor(v, 16, 64);
        if (tid == 0) scores[b * 65 + c] = v;
    }
}

static __device__ __forceinline__ float softplusf(float x) {
    // stable: max(x,0) + log1p(exp(-|x|))
    return fmaxf(x, 0.0f) + log1pf(expf(-fabsf(x)));
}

__global__ __launch_bounds__(64) void loss_kernel(const float* __restrict__ scores,
                                                  float* __restrict__ out) {
    const int b = threadIdx.x;   // 64 threads = 1 wave
    const float* row = scores + b * 65;
    const float pos  = row[b];
    const float negq = row[64];
    float nib = -1e30f;
    #pragma unroll
    for (int c = 0; c < B_SZ; ++c) {
        float v = row[c] - ((c == b) ? 1000000.0f : 0.0f);
        nib = fmaxf(nib, v);
    }
    float t = softplusf(negq - pos) + softplusf(nib - pos);
    t += __shfl_xor(t, 1, 64);
    t += __shfl_xor(t, 2, 64);
    t += __shfl_xor(t, 4, 64);
    t += __shfl_xor(t, 8, 64);
    t += __shfl_xor(t, 16, 64);
    t += __shfl_xor(t, 32, 64);
    if (b == 0) out[0] = t * (0.5f / 64.0f);
}

extern "C" void kernel_launch(void* const* d_in, const int* in_sizes, int n_in,
                              void* d_out, int out_size, void* d_ws, size_t ws_size,
                              hipStream_t stream) {
    const float* q  = (const float*)d_in[0];   // (64, 32, 128)
    const float* dd = (const float*)d_in[1];   // (64, 256, 128)
    const float* nd = (const float*)d_in[2];   // (64, 256, 128)
    float* out = (float*)d_out;

    const int nQ = B_SZ * N_Q * D_DIM;         // 262144
    const int nD = B_SZ * S_D * D_DIM;         // 2097152

    // Workspace layout (bytes): qb | db | ndb | scores
    unsigned short* qb  = (unsigned short*)d_ws;
    unsigned short* db  = qb + nQ;
    unsigned short* ndb = db + nD;
    float* scores = (float*)(ndb + nD);        // 64*65 floats

    cvt_f32_bf16<<<nQ / 1024, 256, 0, stream>>>(q,  qb,  nQ / 4);
    cvt_f32_bf16<<<nD / 1024, 256, 0, stream>>>(dd, db,  nD / 4);
    cvt_f32_bf16<<<nD / 1024, 256, 0, stream>>>(nd, ndb, nD / 4);

    dim3 grid(B_SZ + 1, B_SZ);   // c in 0..64, b in 0..63
    maxsim_kernel<<<grid, 256, 0, stream>>>(qb, db, ndb, scores);

    loss_kernel<<<1, 64, 0, stream>>>(scores, out);
}

// Round 2
// 113.362 us; speedup vs baseline: 1.0883x; 1.0883x over previous
//
#include <hip/hip_runtime.h>
#include <hip/hip_bf16.h>

// Problem constants (B, N, S, D) from reference
#define B_SZ 64
#define N_Q 32
#define S_D 256
#define D_DIM 128

typedef __attribute__((ext_vector_type(8))) short bf16x8;
typedef __attribute__((ext_vector_type(4))) float f32x4;

static __device__ __forceinline__ unsigned short f2bf(float f) {
    __hip_bfloat16 h = __float2bfloat16(f);
    return *reinterpret_cast<unsigned short*>(&h);
}

// Convert queries fp32 -> bf16 (small: 256 blocks)
__global__ __launch_bounds__(256) void cvt_f32_bf16(const float* __restrict__ src,
                                                    unsigned short* __restrict__ dst,
                                                    int n4) {
    int i = blockIdx.x * 256 + threadIdx.x;
    if (i >= n4) return;
    float4 v = reinterpret_cast<const float4*>(src)[i];
    ushort4 o;
    o.x = f2bf(v.x); o.y = f2bf(v.y); o.z = f2bf(v.z); o.w = f2bf(v.w);
    reinterpret_cast<ushort4*>(dst)[i] = o;
}

// Doc-stationary MaxSim.
// idx < 512:  c = idx>>3 (in-batch doc), b-group = idx&7 (8 b's)  -> scores[b*65+c]
// idx >= 512: b = idx-512, neg doc of b                           -> scores[b*65+64]
// Wave w owns s-columns [w*64, w*64+64); its doc slice (64s x 128k bf16) lives in
// 16 bf16x8 registers (Bf), loaded once per WG with in-register fp32->bf16 cvt.
__global__ __launch_bounds__(256) void maxsim_kernel(const unsigned short* __restrict__ Qb,
                                                     const float* __restrict__ Df,
                                                     const float* __restrict__ Nf,
                                                     float* __restrict__ scores) {
    const int idx = blockIdx.x;
    int b0, nb, ccol;
    const float* dptr;
    if (idx < 512) {
        const int c = idx >> 3;
        b0 = (idx & 7) * 8; nb = 8; ccol = c;
        dptr = Df + (size_t)c * S_D * D_DIM;
    } else {
        b0 = idx - 512; nb = 1; ccol = B_SZ;
        dptr = Nf + (size_t)b0 * S_D * D_DIM;
    }

    const int tid  = threadIdx.x;
    const int wave = tid >> 6;
    const int lane = tid & 63;
    const int l15  = lane & 15;
    const int l4   = lane >> 4;         // 0..3
    const int s_base = wave * 64;

    // ---- one-time: doc slice -> registers (B-operand fragments) ----
    // B frag layout: B[k = l4*8 + j][n = l15] = doc[s][k], contiguous along k.
    bf16x8 Bf[4][4];                    // [kk][nt]
    #pragma unroll
    for (int kk = 0; kk < 4; ++kk) {
        const int k0 = kk * 32 + l4 * 8;
        #pragma unroll
        for (int nt = 0; nt < 4; ++nt) {
            const int s = s_base + nt * 16 + l15;
            const float4* p = reinterpret_cast<const float4*>(dptr + (size_t)s * D_DIM + k0);
            float4 x = p[0];
            float4 y = p[1];
            union { bf16x8 v; unsigned short u[8]; } t;
            t.u[0] = f2bf(x.x); t.u[1] = f2bf(x.y); t.u[2] = f2bf(x.z); t.u[3] = f2bf(x.w);
            t.u[4] = f2bf(y.x); t.u[5] = f2bf(y.y); t.u[6] = f2bf(y.z); t.u[7] = f2bf(y.w);
            Bf[kk][nt] = t.v;
        }
    }

    __shared__ float wred[8][4][N_Q];   // [bb][wave][n] row-max of wave's 64-col slice

    const int npairs = (nb + 1) >> 1;
    for (int g = 0; g < npairs; ++g) {
        const int bb0 = 2 * g;
        const int bb1 = (2 * g + 1 < nb) ? 2 * g + 1 : 2 * g;
        const unsigned short* qA = Qb + (size_t)(b0 + bb0) * N_Q * D_DIM;
        const unsigned short* qB = Qb + (size_t)(b0 + bb1) * N_Q * D_DIM;

        f32x4 acc[2][2][4] = {};        // [which b][mt][nt]
        #pragma unroll
        for (int kk = 0; kk < 4; ++kk) {
            const int k0 = kk * 32 + l4 * 8;
            // A frag: A[m=l15][k=l4*8+j], rows mt*16+l15
            bf16x8 aA0 = *reinterpret_cast<const bf16x8*>(qA + (size_t)l15 * D_DIM + k0);
            bf16x8 aA1 = *reinterpret_cast<const bf16x8*>(qA + (size_t)(16 + l15) * D_DIM + k0);
            bf16x8 aB0 = *reinterpret_cast<const bf16x8*>(qB + (size_t)l15 * D_DIM + k0);
            bf16x8 aB1 = *reinterpret_cast<const bf16x8*>(qB + (size_t)(16 + l15) * D_DIM + k0);
            #pragma unroll
            for (int nt = 0; nt < 4; ++nt) {
                acc[0][0][nt] = __builtin_amdgcn_mfma_f32_16x16x32_bf16(aA0, Bf[kk][nt], acc[0][0][nt], 0, 0, 0);
                acc[0][1][nt] = __builtin_amdgcn_mfma_f32_16x16x32_bf16(aA1, Bf[kk][nt], acc[0][1][nt], 0, 0, 0);
                acc[1][0][nt] = __builtin_amdgcn_mfma_f32_16x16x32_bf16(aB0, Bf[kk][nt], acc[1][0][nt], 0, 0, 0);
                acc[1][1][nt] = __builtin_amdgcn_mfma_f32_16x16x32_bf16(aB1, Bf[kk][nt], acc[1][1][nt], 0, 0, 0);
            }
        }

        // per-b reduction: max over this wave's 64 s-columns for each of 32 rows
        #pragma unroll
        for (int h = 0; h < 2; ++h) {
            const int bb = (h == 0) ? bb0 : bb1;
            #pragma unroll
            for (int mt = 0; mt < 2; ++mt) {
                #pragma unroll
                for (int reg = 0; reg < 4; ++reg) {
                    float m = fmaxf(fmaxf(acc[h][mt][0][reg], acc[h][mt][1][reg]),
                                    fmaxf(acc[h][mt][2][reg], acc[h][mt][3][reg]));
                    m = fmaxf(m, __shfl_xor(m, 1, 64));
                    m = fmaxf(m, __shfl_xor(m, 2, 64));
                    m = fmaxf(m, __shfl_xor(m, 4, 64));
                    m = fmaxf(m, __shfl_xor(m, 8, 64));
                    if (l15 == 0) wred[bb][wave][mt * 16 + l4 * 4 + reg] = m;
                }
            }
        }
    }
    __syncthreads();

    // final: max over 4 waves (=> max over all 256 s), sum over 32 rows, write score
    const int bb = tid >> 5;            // 0..7
    const int n  = tid & 31;
    if (bb < nb) {
        float m = fmaxf(fmaxf(wred[bb][0][n], wred[bb][1][n]),
                        fmaxf(wred[bb][2][n], wred[bb][3][n]));
        m += __shfl_xor(m, 1, 64);
        m += __shfl_xor(m, 2, 64);
        m += __shfl_xor(m, 4, 64);
        m += __shfl_xor(m, 8, 64);
        m += __shfl_xor(m, 16, 64);
        if (n == 0) scores[(size_t)(b0 + bb) * 65 + ccol] = m;
    }
}

static __device__ __forceinline__ float softplusf(float x) {
    return fmaxf(x, 0.0f) + log1pf(expf(-fabsf(x)));
}

__global__ __launch_bounds__(64) void loss_kernel(const float* __restrict__ scores,
                                                  float* __restrict__ out) {
    const int b = threadIdx.x;          // 64 threads = 1 wave
    const float* row = scores + b * 65;
    const float pos  = row[b];
    const float negq = row[64];
    float nib = -1e30f;
    #pragma unroll
    for (int c = 0; c < B_SZ; ++c) {
        float v = row[c] - ((c == b) ? 1000000.0f : 0.0f);
        nib = fmaxf(nib, v);
    }
    float t = softplusf(negq - pos) + softplusf(nib - pos);
    t += __shfl_xor(t, 1, 64);
    t += __shfl_xor(t, 2, 64);
    t += __shfl_xor(t, 4, 64);
    t += __shfl_xor(t, 8, 64);
    t += __shfl_xor(t, 16, 64);
    t += __shfl_xor(t, 32, 64);
    if (b == 0) out[0] = t * (0.5f / 64.0f);
}

extern "C" void kernel_launch(void* const* d_in, const int* in_sizes, int n_in,
                              void* d_out, int out_size, void* d_ws, size_t ws_size,
                              hipStream_t stream) {
    const float* q  = (const float*)d_in[0];   // (64, 32, 128)
    const float* dd = (const float*)d_in[1];   // (64, 256, 128)
    const float* nd = (const float*)d_in[2];   // (64, 256, 128)
    float* out = (float*)d_out;

    const int nQ = B_SZ * N_Q * D_DIM;         // 262144

    // Workspace: qb (bf16) | scores (64*65 fp32)
    unsigned short* qb = (unsigned short*)d_ws;
    float* scores = (float*)(qb + nQ);

    cvt_f32_bf16<<<nQ / 1024, 256, 0, stream>>>(q, qb, nQ / 4);

    maxsim_kernel<<<512 + B_SZ, 256, 0, stream>>>(qb, dd, nd, scores);

    loss_kernel<<<1, 64, 0, stream>>>(scores, out);
}